// Round 7
// baseline (407.861 us; speedup 1.0000x reference)
//
#include <hip/hip_runtime.h>
#include <stdint.h>

#define DM_ 256
#define H_ 4
#define M_ 4096
#define KN_ 16
#define B_ 2
#define MK_ (M_*KN_)

typedef __attribute__((ext_vector_type(8))) short short8;
typedef __attribute__((ext_vector_type(4))) float f32x4;
typedef __attribute__((ext_vector_type(4))) unsigned short u16x4;

static __device__ __forceinline__ unsigned short f2bf(float x) {
  union { float f; uint32_t u; } v; v.f = x;
  uint32_t u = v.u + (0x7FFFu + ((v.u >> 16) & 1u));  // RNE
  return (unsigned short)(u >> 16);
}
static __device__ __forceinline__ float u2f(uint32_t u) {
  union { uint32_t u; float f; } v; v.u = u; return v.f;
}

// XOR swizzle for [col][k] bf16 tiles (row stride 512 B), bank-floor b128 reads/writes.
static __device__ __forceinline__ int swz512(int col, int kbyte) {
  int f = ((col >> 2) & 7) ^ ((col & 1) << 2);
  return (col << 9) + (kbyte ^ (f << 4));
}

// ---- prep2: weight products, fragment-linear bf16, fused biases ------------------------
__global__ void prep2(const float* __restrict__ Wq, const float* __restrict__ bq,
                      const float* __restrict__ Wk, const float* __restrict__ Wv,
                      const float* __restrict__ bv, const float* __restrict__ Wm,
                      const float* __restrict__ bm,
                      unsigned short* __restrict__ W2T, unsigned short* __restrict__ Wmv,
                      float* __restrict__ qb2, float* __restrict__ btot) {
  int t = blockIdx.x * 512 + threadIdx.x;
  if (t < 262144) {                       // W2T fragment-linear [kstep8][rowblk64][lane][8]
    int j = t & 7, lane = (t >> 3) & 63, rowblk = (t >> 9) & 63, kstep = t >> 15;
    int row = rowblk * 16 + (lane & 15);
    int k = kstep * 32 + (lane >> 4) * 8 + j;
    int h = row >> 8, c = row & 255;
    float v = 0.f;
#pragma unroll 8
    for (int d = 0; d < 64; ++d) v += Wq[(4 * d + h) * 256 + k] * Wk[(4 * d + h) * 256 + c];
    W2T[t] = f2bf(v);
  } else if (t < 524288) {                // Wmv fragment-linear [kstep32][rowblk16][lane][8]
    int e = t - 262144;
    int j = e & 7, lane = (e >> 3) & 63, rowblk = (e >> 9) & 15, kstep = e >> 13;
    int o = rowblk * 16 + (lane & 15);
    int kidx = kstep * 32 + (lane >> 4) * 8 + j;
    int c = kidx >> 2, h = kidx & 3;
    float v = 0.f;
#pragma unroll 8
    for (int d = 0; d < 64; ++d) v += Wm[o * 256 + 4 * d + h] * Wv[(4 * d + h) * 256 + c];
    Wmv[e] = f2bf(v);
  } else if (t < 525312) {
    int r = t - 524288; int h = r >> 8, c = r & 255;
    float v = 0.f;
#pragma unroll 8
    for (int d = 0; d < 64; ++d) v += bq[4 * d + h] * Wk[(4 * d + h) * 256 + c];
    qb2[r] = v;
  } else if (t < 525568) {
    int o = t - 525312;
    float v = bm[o];
#pragma unroll 8
    for (int c2 = 0; c2 < 256; ++c2) v += Wm[o * 256 + c2] * bv[c2];
    btot[o] = v;
  }
}

// ---- qw_gemm: qW[b][r=h*256+c][m] (bf16) = W2T × query + qb2 ; grid = B*4rt*128mt ------
__global__ __launch_bounds__(512)
void qw_gemm(const float* __restrict__ query, const unsigned short* __restrict__ W2T,
             const float* __restrict__ qb2, unsigned short* __restrict__ qWbuf) {
  __shared__ unsigned short Xl[32 * 256];
  const int tid = threadIdx.x;
  const int lane = tid & 63, wid = tid >> 6;
  const int wr = wid >> 1, wc = wid & 1;
  const int mt = blockIdx.x & 127;
  const int rt = (blockIdx.x >> 7) & 3;
  const int b = blockIdx.x >> 9;
  const int m0 = mt * 32;
  const float* Xb = query + (size_t)b * DM_ * M_ + m0;
  const int c4 = 4 * (tid & 7);
  const int ch0 = 4 * (tid >> 3);
  float4 f[4];
#pragma unroll
  for (int i = 0; i < 4; ++i) f[i] = *(const float4*)(Xb + (size_t)(ch0 + i) * M_ + c4);
#pragma unroll
  for (int j = 0; j < 4; ++j) {
    u16x4 u = { f2bf(((const float*)&f[0])[j]), f2bf(((const float*)&f[1])[j]),
                f2bf(((const float*)&f[2])[j]), f2bf(((const float*)&f[3])[j]) };
    *(u16x4*)((char*)Xl + swz512(c4 + j, 2 * ch0)) = u;
  }
  __syncthreads();
  f32x4 acc[4] = {};
  const int bcol = wc * 16 + (lane & 15);
  const int rdk = 16 * (lane >> 4);
  short8 a_cur[4], a_nxt[4];
#pragma unroll
  for (int fi = 0; fi < 4; ++fi)
    a_cur[fi] = *(const short8*)(W2T + (size_t)(((rt * 16 + wr * 4 + fi) * 64 + lane) * 8));
#pragma unroll
  for (int kgs = 0; kgs < 8; ++kgs) {
    if (kgs < 7) {
#pragma unroll
      for (int fi = 0; fi < 4; ++fi)
        a_nxt[fi] = *(const short8*)(W2T + (size_t)((((kgs + 1) * 64 + rt * 16 + wr * 4 + fi) * 64 + lane) * 8));
    }
    short8 bb = *(const short8*)((const char*)Xl + swz512(bcol, 64 * kgs + rdk));
#pragma unroll
    for (int fi = 0; fi < 4; ++fi)
      acc[fi] = __builtin_amdgcn_mfma_f32_16x16x32_bf16(a_cur[fi], bb, acc[fi], 0, 0, 0);
#pragma unroll
    for (int fi = 0; fi < 4; ++fi) a_cur[fi] = a_nxt[fi];
  }
#pragma unroll
  for (int fi = 0; fi < 4; ++fi) {
#pragma unroll
    for (int r = 0; r < 4; ++r) {
      const int rr = rt * 256 + wr * 64 + fi * 16 + (lane >> 4) * 4 + r;
      qWbuf[(size_t)(b * 1024 + rr) * M_ + m0 + bcol] = f2bf(acc[fi][r] + qb2[rr]);
    }
  }
}

// ---- score_part: split-K partial scores, fully contiguous key streaming ----------------
// grid = B*8cg*32ms = 512 blocks, 512 threads. Block: chans [cg*32,+32), m [ms*128,+128).
// ps[h][kk-slice] kept in VGPRs; key via asm ring depth 12 (static vmcnt);
// per-chan qW from a 32KB LDS slab staged once. Key reads: 1KB/wave-instr, 8KB runs/chan.
__global__ __launch_bounds__(512, 4)
void score_part(const float* __restrict__ key, const unsigned short* __restrict__ qW,
                float* __restrict__ psbuf) {
  __shared__ unsigned short qsl[32 * 128 * 4];   // [c][m][h] bf16, 32 KB
  const int tid = threadIdx.x;
  const int bid = blockIdx.x;
  const int cg = bid & 7, msb = (bid >> 3) & 31, b = bid >> 8;
  const int m0 = msb * 128, C0 = cg * 32;
  // stage qW slab: 128 rows (h,c) x 128 m, 256B runs
  {
    const int row = tid >> 2, part = tid & 3;
    const int h = row >> 5, c = row & 31;
    const unsigned short* src = qW + (size_t)(b * 1024 + h * 256 + C0 + c) * M_ + m0 + part * 32;
#pragma unroll
    for (int p = 0; p < 4; ++p) {
      uint4 v = *(const uint4*)(src + p * 8);
      const uint32_t* vu = (const uint32_t*)&v;
#pragma unroll
      for (int e = 0; e < 4; ++e) {
        const int mm = part * 32 + p * 8 + e * 2;
        qsl[(c * 128 + mm) * 4 + h]     = (unsigned short)(vu[e] & 0xffffu);
        qsl[(c * 128 + mm + 1) * 4 + h] = (unsigned short)(vu[e] >> 16);
      }
    }
  }
  __syncthreads();
  const int mq = tid >> 2;                 // 0..127
  const int kq = (tid & 3) * 4;            // kk slice base
  const float* kp = key + (size_t)(b * 256 + C0) * 65536 + (size_t)m0 * 16;
  const uint32_t voff = (uint32_t)((mq * 16 + kq) * 4);
  f32x4 K[12];
#define GK(s, cc) asm volatile("global_load_dwordx4 %0, %1, %2" : "=v"(K[s]) : "v"(voff), "s"(kp + (size_t)(cc) * 65536))
  GK(0,0); GK(1,1); GK(2,2); GK(3,3); GK(4,4); GK(5,5);
  GK(6,6); GK(7,7); GK(8,8); GK(9,9); GK(10,10); GK(11,11);
  f32x4 ps0 = {}, ps1 = {}, ps2 = {}, ps3 = {};
#define AIT(c, n) { \
    asm volatile("s_waitcnt vmcnt(" #n ")" ::: "memory"); \
    __builtin_amdgcn_sched_barrier(0); \
    uint2 qv = *(const uint2*)&qsl[((c) * 128 + mq) * 4]; \
    float h0 = u2f(qv.x << 16), h1 = u2f(qv.x & 0xffff0000u); \
    float h2 = u2f(qv.y << 16), h3 = u2f(qv.y & 0xffff0000u); \
    ps0 += K[(c) % 12] * h0; ps1 += K[(c) % 12] * h1; \
    ps2 += K[(c) % 12] * h2; ps3 += K[(c) % 12] * h3; \
    if ((c) < 20) { GK((c) % 12, (c) + 12); } \
  }
  AIT(0,11) AIT(1,11) AIT(2,11) AIT(3,11) AIT(4,11) AIT(5,11) AIT(6,11) AIT(7,11)
  AIT(8,11) AIT(9,11) AIT(10,11) AIT(11,11) AIT(12,11) AIT(13,11) AIT(14,11) AIT(15,11)
  AIT(16,11) AIT(17,11) AIT(18,11) AIT(19,11) AIT(20,11) AIT(21,10) AIT(22,9) AIT(23,8)
  AIT(24,7) AIT(25,6) AIT(26,5) AIT(27,4) AIT(28,3) AIT(29,2) AIT(30,1) AIT(31,0)
#undef AIT
#undef GK
  // write ps[b][cg][m][kk][h] f32, 64B contiguous per thread
  float* pso = psbuf + ((size_t)((b * 8 + cg) * 4096 + m0 + mq) * 16 + kq) * 4;
#pragma unroll
  for (int j = 0; j < 4; ++j) {
    f32x4 o = {ps0[j], ps1[j], ps2[j], ps3[j]};
    *(f32x4*)(pso + j * 4) = o;
  }
}

// ---- softmax_k: reduce 8 partials, softmax per (m,h) in-thread, emit prob bf16 + psum --
// grid = B*M/32 = 256 blocks, 512 threads: tid = mloc*16 + cp*4 + h.
__global__ __launch_bounds__(512)
void softmax_k(const float* __restrict__ psbuf, unsigned short* __restrict__ prob,
               float* __restrict__ psum) {
  const int tid = threadIdx.x, bid = blockIdx.x;
  const int b = bid >> 7;
  const int m = (bid & 127) * 32 + (tid >> 4);
  const int cp = (tid >> 2) & 3, h = tid & 3;
  float s[16];
#pragma unroll
  for (int kk = 0; kk < 16; ++kk) s[kk] = 0.f;
#pragma unroll
  for (int gi = 0; gi < 2; ++gi) {
    const int g = cp * 2 + gi;
    const float* pp = psbuf + (size_t)((b * 8 + g) * 4096 + m) * 64 + h;
#pragma unroll
    for (int kk = 0; kk < 16; ++kk) s[kk] += pp[kk * 4];
  }
#pragma unroll
  for (int kk = 0; kk < 16; ++kk) {
    s[kk] += __shfl_xor(s[kk], 4);
    s[kk] += __shfl_xor(s[kk], 8);
    s[kk] *= 0.125f;                       // 1/sqrt(64)
  }
  float mx = s[0];
#pragma unroll
  for (int kk = 1; kk < 16; ++kk) mx = fmaxf(mx, s[kk]);
  float sm = 0.f;
#pragma unroll
  for (int kk = 0; kk < 16; ++kk) { s[kk] = __expf(s[kk] - mx); sm += s[kk]; }
  const float inv = 1.f / sm;
#pragma unroll
  for (int kk = 0; kk < 16; ++kk) s[kk] *= inv;
  if (cp == 0) {
    unsigned short o16[16];
#pragma unroll
    for (int kk = 0; kk < 16; ++kk) o16[kk] = f2bf(s[kk]);
    unsigned short* dst = prob + ((size_t)(b * 4096 + m) * 4 + h) * 16;
    *(uint4*)dst = *(const uint4*)&o16[0];
    *(uint4*)(dst + 8) = *(const uint4*)&o16[8];
  }
#pragma unroll
  for (int kk = 0; kk < 16; ++kk) {        // reduce prob over h lanes for psum
    s[kk] += __shfl_xor(s[kk], 1);
    s[kk] += __shfl_xor(s[kk], 2);
  }
  if (cp == 0 && h == 0) {
    float* dst = psum + ((size_t)b * M_ + m) * 16;
#pragma unroll
    for (int j = 0; j < 4; ++j) {
      f32x4 o = {s[j * 4], s[j * 4 + 1], s[j * 4 + 2], s[j * 4 + 3]};
      *(f32x4*)(dst + j * 4) = o;
    }
  }
}

// ---- pv_part: contiguous value streaming + prob contraction, LDS-collect writeout ------
// grid = 512 ((b*32+ms)*8+cg so cg-siblings share prob in L2), 512 threads.
__global__ __launch_bounds__(512, 4)
void pv_part(const float* __restrict__ value, const unsigned short* __restrict__ prob,
             unsigned short* __restrict__ pvbuf) {
  __shared__ unsigned short pvt[128 * 132];      // [m][ch-local], padded row 132
  const int tid = threadIdx.x;
  const int bid = blockIdx.x;
  const int cg = bid & 7, msb = (bid >> 3) & 31, b = bid >> 8;
  const int m0 = msb * 128, C0 = cg * 32;
  const int mq = tid >> 2, kq4 = tid & 3;
  // prob loads first (asm) so their wait leaves the V ring outstanding
  const unsigned short* pb = prob + (size_t)(b * 4096 + m0) * 64;
  const uint32_t pvo = (uint32_t)(mq * 128 + kq4 * 8);
  uint2 pw0, pw1, pw2, pw3;
  asm volatile("global_load_dwordx2 %0, %1, %2"           : "=v"(pw0) : "v"(pvo), "s"(pb));
  asm volatile("global_load_dwordx2 %0, %1, %2 offset:32" : "=v"(pw1) : "v"(pvo), "s"(pb));
  asm volatile("global_load_dwordx2 %0, %1, %2 offset:64" : "=v"(pw2) : "v"(pvo), "s"(pb));
  asm volatile("global_load_dwordx2 %0, %1, %2 offset:96" : "=v"(pw3) : "v"(pvo), "s"(pb));
  const float* vp = value + (size_t)(b * 256 + C0) * 65536 + (size_t)m0 * 16;
  const uint32_t voff = (uint32_t)((mq * 16 + kq4 * 4) * 4);
  f32x4 V[12];
#define GV(s, cc) asm volatile("global_load_dwordx4 %0, %1, %2" : "=v"(V[s]) : "v"(voff), "s"(vp + (size_t)(cc) * 65536))
  GV(0,0); GV(1,1); GV(2,2); GV(3,3); GV(4,4); GV(5,5);
  GV(6,6); GV(7,7); GV(8,8); GV(9,9); GV(10,10); GV(11,11);
  asm volatile("s_waitcnt vmcnt(12)" ::: "memory");   // prob ready; V ring in flight
  __builtin_amdgcn_sched_barrier(0);
  f32x4 pr0 = {u2f(pw0.x << 16), u2f(pw0.x & 0xffff0000u), u2f(pw0.y << 16), u2f(pw0.y & 0xffff0000u)};
  f32x4 pr1 = {u2f(pw1.x << 16), u2f(pw1.x & 0xffff0000u), u2f(pw1.y << 16), u2f(pw1.y & 0xffff0000u)};
  f32x4 pr2 = {u2f(pw2.x << 16), u2f(pw2.x & 0xffff0000u), u2f(pw2.y << 16), u2f(pw2.y & 0xffff0000u)};
  f32x4 pr3 = {u2f(pw3.x << 16), u2f(pw3.x & 0xffff0000u), u2f(pw3.y << 16), u2f(pw3.y & 0xffff0000u)};
  const bool k0 = (kq4 == 0), k1 = (kq4 == 1), k2 = (kq4 == 2);
#define CIT(c, n) { \
    asm volatile("s_waitcnt vmcnt(" #n ")" ::: "memory"); \
    __builtin_amdgcn_sched_barrier(0); \
    f32x4 vv = V[(c) % 12]; \
    float p0 = vv[0]*pr0[0] + vv[1]*pr0[1] + vv[2]*pr0[2] + vv[3]*pr0[3]; \
    float p1 = vv[0]*pr1[0] + vv[1]*pr1[1] + vv[2]*pr1[2] + vv[3]*pr1[3]; \
    float p2 = vv[0]*pr2[0] + vv[1]*pr2[1] + vv[2]*pr2[2] + vv[3]*pr2[3]; \
    float p3 = vv[0]*pr3[0] + vv[1]*pr3[1] + vv[2]*pr3[2] + vv[3]*pr3[3]; \
    p0 += __shfl_xor(p0, 1); p0 += __shfl_xor(p0, 2); \
    p1 += __shfl_xor(p1, 1); p1 += __shfl_xor(p1, 2); \
    p2 += __shfl_xor(p2, 1); p2 += __shfl_xor(p2, 2); \
    p3 += __shfl_xor(p3, 1); p3 += __shfl_xor(p3, 2); \
    float psel = k0 ? p0 : (k1 ? p1 : (k2 ? p2 : p3)); \
    pvt[mq * 132 + (c) * 4 + kq4] = f2bf(psel); \
    if ((c) < 20) { GV((c) % 12, (c) + 12); } \
  }
  CIT(0,11) CIT(1,11) CIT(2,11) CIT(3,11) CIT(4,11) CIT(5,11) CIT(6,11) CIT(7,11)
  CIT(8,11) CIT(9,11) CIT(10,11) CIT(11,11) CIT(12,11) CIT(13,11) CIT(14,11) CIT(15,11)
  CIT(16,11) CIT(17,11) CIT(18,11) CIT(19,11) CIT(20,11) CIT(21,10) CIT(22,9) CIT(23,8)
  CIT(24,7) CIT(25,6) CIT(26,5) CIT(27,4) CIT(28,3) CIT(29,2) CIT(30,1) CIT(31,0)
#undef CIT
#undef GV
  __syncthreads();
  // writeout: pv[b][m][ch=(C0+c)*4+h] bf16, 64B per thread, 256B runs per row
  {
    const int row = tid >> 2, part = tid & 3;
    unsigned short* dst = pvbuf + (size_t)(b * 4096 + m0 + row) * 1024 + C0 * 4 + part * 32;
    const unsigned short* srcl = &pvt[row * 132 + part * 32];
#pragma unroll
    for (int j = 0; j < 4; ++j)
      *(uint4*)(dst + j * 8) = *(const uint4*)(srcl + j * 8);
  }
}

// ---- out_gemm: out[b][o][m] = Wmv × pv + btot ; grid = B*256 (16-col tiles), K=1024 ----
__global__ __launch_bounds__(512)
void out_gemm(const unsigned short* __restrict__ pvbuf, const unsigned short* __restrict__ Wmv,
              const float* __restrict__ btot, float* __restrict__ Out) {
  __shared__ unsigned short Xl[2][16 * 256];
  const int tid = threadIdx.x;
  const int lane = tid & 63, wid = tid >> 6;
  const int b = blockIdx.x >> 8;
  const int m0 = (blockIdx.x & 255) * 16;
  const int scol = tid & 15, sq = tid >> 4;
  const int bcol = lane & 15;
  const int rdk = 16 * (lane >> 4);
  f32x4 acc[2] = {};
  for (int kp = 0; kp < 4; ++kp) {
    {
      const unsigned short* src = pvbuf + ((size_t)(b * M_ + m0 + scol) * 1024 + kp * 256 + sq * 8);
      uint4 v0 = *(const uint4*)src;
      *(uint4*)((char*)Xl[kp & 1] + swz512(scol, sq * 16)) = v0;
    }
    __syncthreads();
    short8 a_cur[2], a_nxt[2];
#pragma unroll
    for (int fi = 0; fi < 2; ++fi)
      a_cur[fi] = *(const short8*)(Wmv + (size_t)((((kp * 8) * 16 + wid * 2 + fi) * 64 + lane) * 8));
#pragma unroll
    for (int kgs = 0; kgs < 8; ++kgs) {
      if (kgs < 7) {
#pragma unroll
        for (int fi = 0; fi < 2; ++fi)
          a_nxt[fi] = *(const short8*)(Wmv + (size_t)((((kp * 8 + kgs + 1) * 16 + wid * 2 + fi) * 64 + lane) * 8));
      }
      short8 bb = *(const short8*)((const char*)Xl[kp & 1] + swz512(bcol, 64 * kgs + rdk));
#pragma unroll
      for (int fi = 0; fi < 2; ++fi)
        acc[fi] = __builtin_amdgcn_mfma_f32_16x16x32_bf16(a_cur[fi], bb, acc[fi], 0, 0, 0);
#pragma unroll
      for (int fi = 0; fi < 2; ++fi) a_cur[fi] = a_nxt[fi];
    }
    if (kp < 3) __syncthreads();
  }
#pragma unroll
  for (int fi = 0; fi < 2; ++fi) {
#pragma unroll
    for (int r = 0; r < 4; ++r) {
      const int o = (wid * 2 + fi) * 16 + (lane >> 4) * 4 + r;
      Out[(size_t)(b * DM_ + o) * M_ + m0 + bcol] = acc[fi][r] + btot[o];
    }
  }
}

extern "C" void kernel_launch(void* const* d_in, const int* in_sizes, int n_in,
                              void* d_out, int out_size, void* d_ws, size_t ws_size,
                              hipStream_t stream) {
  const float* query = (const float*)d_in[0];
  const float* key   = (const float*)d_in[1];
  const float* value = (const float*)d_in[2];
  const float* Wq = (const float*)d_in[3];
  const float* bq = (const float*)d_in[4];
  const float* Wk = (const float*)d_in[5];
  const float* bk = (const float*)d_in[6];  (void)bk;  // folded: softmax-invariant
  const float* Wv = (const float*)d_in[7];
  const float* bv = (const float*)d_in[8];
  const float* Wm = (const float*)d_in[9];
  const float* bm = (const float*)d_in[10];
  float* out  = (float*)d_out;
  float* psum = out + (size_t)B_ * DM_ * M_;   // outputs concatenated: out then prob_sum

  // ---- workspace layout (34.6 MB, same as R4-R6) ----
  // region0: W2T 512K | Wmv 512K | qb2 4K | btot 1K          (1.05 MB)
  // region1: qW 16.78 MB  (dead after score_part; prob bf16 1 MB aliases its head)
  // region2: ps f32 16.78 MB (dead after softmax_k; pv bf16 16.78 MB aliases it)
  const size_t Wmv_off  = 524288;
  const size_t qb2_off  = 1048576;
  const size_t btot_off = 1052672;
  const size_t qW_off   = 1053696;
  const size_t ps_off   = qW_off + (size_t)B_ * 1024 * M_ * 2;

  unsigned short* W2T   = (unsigned short*)d_ws;
  unsigned short* Wmv   = (unsigned short*)((char*)d_ws + Wmv_off);
  float* qb2            = (float*)((char*)d_ws + qb2_off);
  float* btot           = (float*)((char*)d_ws + btot_off);
  unsigned short* qWbuf = (unsigned short*)((char*)d_ws + qW_off);
  unsigned short* prob  = qWbuf;                                   // alias (qW dead)
  float* psbuf          = (float*)((char*)d_ws + ps_off);
  unsigned short* pvbuf = (unsigned short*)((char*)d_ws + ps_off); // alias (ps dead)

  prep2<<<dim3(1027), dim3(512), 0, stream>>>(Wq, bq, Wk, Wv, bv, Wm, bm, W2T, Wmv, qb2, btot);
  qw_gemm<<<dim3(B_ * 4 * 128), dim3(512), 0, stream>>>(query, W2T, qb2, qWbuf);
  score_part<<<dim3(512), dim3(512), 0, stream>>>(key, qWbuf, psbuf);
  softmax_k<<<dim3(256), dim3(512), 0, stream>>>(psbuf, prob, psum);
  pv_part<<<dim3(512), dim3(512), 0, stream>>>(value, prob, pvbuf);
  out_gemm<<<dim3(B_ * 256), dim3(512), 0, stream>>>(pvbuf, Wmv, btot, out);
}

// Round 8
// 134.682 us; speedup vs baseline: 3.0283x; 3.0283x over previous
//
#include <hip/hip_runtime.h>
#include <stdint.h>

#define DM_ 256
#define H_ 4
#define M_ 4096
#define KN_ 16
#define B_ 2
#define MK_ (M_*KN_)

typedef __attribute__((ext_vector_type(8))) short short8;
typedef __attribute__((ext_vector_type(4))) float f32x4;
typedef __attribute__((ext_vector_type(4))) unsigned short u16x4;

static __device__ __forceinline__ unsigned short f2bf(float x) {
  union { float f; uint32_t u; } v; v.f = x;
  uint32_t u = v.u + (0x7FFFu + ((v.u >> 16) & 1u));  // RNE
  return (unsigned short)(u >> 16);
}
static __device__ __forceinline__ float u2f(uint32_t u) {
  union { uint32_t u; float f; } v; v.u = u; return v.f;
}

// XOR swizzle for [col][k] bf16 tiles (row stride 512 B), bank-floor b128 reads/writes.
static __device__ __forceinline__ int swz512(int col, int kbyte) {
  int f = ((col >> 2) & 7) ^ ((col & 1) << 2);
  return (col << 9) + (kbyte ^ (f << 4));
}

// ---- prep2: weight products, fragment-linear bf16, fused biases ------------------------
__global__ void prep2(const float* __restrict__ Wq, const float* __restrict__ bq,
                      const float* __restrict__ Wk, const float* __restrict__ Wv,
                      const float* __restrict__ bv, const float* __restrict__ Wm,
                      const float* __restrict__ bm,
                      unsigned short* __restrict__ W2T, unsigned short* __restrict__ Wmv,
                      float* __restrict__ qb2, float* __restrict__ btot) {
  int t = blockIdx.x * 512 + threadIdx.x;
  if (t < 262144) {                       // W2T fragment-linear [kstep8][rowblk64][lane][8]
    int j = t & 7, lane = (t >> 3) & 63, rowblk = (t >> 9) & 63, kstep = t >> 15;
    int row = rowblk * 16 + (lane & 15);
    int k = kstep * 32 + (lane >> 4) * 8 + j;
    int h = row >> 8, c = row & 255;
    float v = 0.f;
#pragma unroll 8
    for (int d = 0; d < 64; ++d) v += Wq[(4 * d + h) * 256 + k] * Wk[(4 * d + h) * 256 + c];
    W2T[t] = f2bf(v);
  } else if (t < 524288) {                // Wmv fragment-linear [kstep32][rowblk16][lane][8]
    int e = t - 262144;
    int j = e & 7, lane = (e >> 3) & 63, rowblk = (e >> 9) & 15, kstep = e >> 13;
    int o = rowblk * 16 + (lane & 15);
    int kidx = kstep * 32 + (lane >> 4) * 8 + j;
    int c = kidx >> 2, h = kidx & 3;
    float v = 0.f;
#pragma unroll 8
    for (int d = 0; d < 64; ++d) v += Wm[o * 256 + 4 * d + h] * Wv[(4 * d + h) * 256 + c];
    Wmv[e] = f2bf(v);
  } else if (t < 525312) {
    int r = t - 524288; int h = r >> 8, c = r & 255;
    float v = 0.f;
#pragma unroll 8
    for (int d = 0; d < 64; ++d) v += bq[4 * d + h] * Wk[(4 * d + h) * 256 + c];
    qb2[r] = v;
  } else if (t < 525568) {
    int o = t - 525312;
    float v = bm[o];
#pragma unroll 8
    for (int c2 = 0; c2 < 256; ++c2) v += Wm[o * 256 + c2] * bv[c2];
    btot[o] = v;
  }
}

// ---- qw_gemm: qW[b][r=h*256+c][m] (bf16) = W2T × query + qb2 ; grid = B*4rt*128mt ------
__global__ __launch_bounds__(512)
void qw_gemm(const float* __restrict__ query, const unsigned short* __restrict__ W2T,
             const float* __restrict__ qb2, unsigned short* __restrict__ qWbuf) {
  __shared__ unsigned short Xl[32 * 256];
  const int tid = threadIdx.x;
  const int lane = tid & 63, wid = tid >> 6;
  const int wr = wid >> 1, wc = wid & 1;
  const int mt = blockIdx.x & 127;
  const int rt = (blockIdx.x >> 7) & 3;
  const int b = blockIdx.x >> 9;
  const int m0 = mt * 32;
  const float* Xb = query + (size_t)b * DM_ * M_ + m0;
  const int c4 = 4 * (tid & 7);
  const int ch0 = 4 * (tid >> 3);
  float4 f[4];
#pragma unroll
  for (int i = 0; i < 4; ++i) f[i] = *(const float4*)(Xb + (size_t)(ch0 + i) * M_ + c4);
#pragma unroll
  for (int j = 0; j < 4; ++j) {
    u16x4 u = { f2bf(((const float*)&f[0])[j]), f2bf(((const float*)&f[1])[j]),
                f2bf(((const float*)&f[2])[j]), f2bf(((const float*)&f[3])[j]) };
    *(u16x4*)((char*)Xl + swz512(c4 + j, 2 * ch0)) = u;
  }
  __syncthreads();
  f32x4 acc[4] = {};
  const int bcol = wc * 16 + (lane & 15);
  const int rdk = 16 * (lane >> 4);
  short8 a_cur[4], a_nxt[4];
#pragma unroll
  for (int fi = 0; fi < 4; ++fi)
    a_cur[fi] = *(const short8*)(W2T + (size_t)(((rt * 16 + wr * 4 + fi) * 64 + lane) * 8));
#pragma unroll
  for (int kgs = 0; kgs < 8; ++kgs) {
    if (kgs < 7) {
#pragma unroll
      for (int fi = 0; fi < 4; ++fi)
        a_nxt[fi] = *(const short8*)(W2T + (size_t)((((kgs + 1) * 64 + rt * 16 + wr * 4 + fi) * 64 + lane) * 8));
    }
    short8 bb = *(const short8*)((const char*)Xl + swz512(bcol, 64 * kgs + rdk));
#pragma unroll
    for (int fi = 0; fi < 4; ++fi)
      acc[fi] = __builtin_amdgcn_mfma_f32_16x16x32_bf16(a_cur[fi], bb, acc[fi], 0, 0, 0);
#pragma unroll
    for (int fi = 0; fi < 4; ++fi) a_cur[fi] = a_nxt[fi];
  }
#pragma unroll
  for (int fi = 0; fi < 4; ++fi) {
#pragma unroll
    for (int r = 0; r < 4; ++r) {
      const int rr = rt * 256 + wr * 64 + fi * 16 + (lane >> 4) * 4 + r;
      qWbuf[(size_t)(b * 1024 + rr) * M_ + m0 + bcol] = f2bf(acc[fi][r] + qb2[rr]);
    }
  }
}

// ---- score_part: split-K partial scores, contiguous key streaming, compiler-pipelined --
// grid = B*8cg*32ms = 512 blocks, 512 threads. Block: chans [cg*32,+32), m [ms*128,+128).
// Per-block addresses span 8KB x 32 channels (channel-select bits vary) -> TLP suffices;
// #pragma unroll 8 gives 8 independent loads per body for the compiler to batch.
__global__ __launch_bounds__(512)
void score_part(const float* __restrict__ key, const unsigned short* __restrict__ qW,
                float* __restrict__ psbuf) {
  __shared__ unsigned short qsl[32 * 520];       // [c][m*4+h], 520-short rows (pad 8)
  const int tid = threadIdx.x;
  const int bid = blockIdx.x;
  const int cg = bid & 7, msb = (bid >> 3) & 31, b = bid >> 8;
  const int m0 = msb * 128, C0 = cg * 32;
  // stage qW slab: 128 rows (h,c) x 128 m, 256B-coalesced reads, padded LDS scatter
  {
    const int row = tid >> 2, part = tid & 3;
    const int h = row >> 5, c = row & 31;
    const unsigned short* src = qW + (size_t)(b * 1024 + h * 256 + C0 + c) * M_ + m0 + part * 32;
#pragma unroll
    for (int p = 0; p < 4; ++p) {
      uint4 v = *(const uint4*)(src + p * 8);
      const uint32_t* vu = (const uint32_t*)&v;
#pragma unroll
      for (int e = 0; e < 4; ++e) {
        const int mm = part * 32 + p * 8 + e * 2;
        qsl[c * 520 + mm * 4 + h]       = (unsigned short)(vu[e] & 0xffffu);
        qsl[c * 520 + (mm + 1) * 4 + h] = (unsigned short)(vu[e] >> 16);
      }
    }
  }
  __syncthreads();
  const int mq = tid >> 2;                 // 0..127
  const int kq = (tid & 3) * 4;            // kk slice base
  const float* kp = key + (size_t)(b * 256 + C0) * 65536 + (size_t)m0 * 16;
  const int moff = mq * 16 + kq;
  f32x4 ps0 = {}, ps1 = {}, ps2 = {}, ps3 = {};
#pragma unroll 8
  for (int c = 0; c < 32; ++c) {
    const f32x4 kv = *(const f32x4*)(kp + (size_t)c * 65536 + moff);
    const uint2 qv = *(const uint2*)&qsl[c * 520 + mq * 4];
    const float h0 = u2f(qv.x << 16), h1 = u2f(qv.x & 0xffff0000u);
    const float h2 = u2f(qv.y << 16), h3 = u2f(qv.y & 0xffff0000u);
    ps0 += kv * h0; ps1 += kv * h1; ps2 += kv * h2; ps3 += kv * h3;
  }
  // write ps[b][cg][m][kk][h] f32, 64B contiguous per thread, 4KB/wave
  float* pso = psbuf + ((size_t)((b * 8 + cg) * 4096 + m0 + mq) * 16 + kq) * 4;
#pragma unroll
  for (int j = 0; j < 4; ++j) {
    f32x4 o = {ps0[j], ps1[j], ps2[j], ps3[j]};
    *(f32x4*)(pso + j * 4) = o;
  }
}

// ---- softmax_k: reduce 8 partials, softmax per (m,h) in-thread, emit prob bf16 + psum --
// grid = B*M/32 = 256 blocks, 512 threads: tid = mloc*16 + cp*4 + h.
__global__ __launch_bounds__(512)
void softmax_k(const float* __restrict__ psbuf, unsigned short* __restrict__ prob,
               float* __restrict__ psum) {
  const int tid = threadIdx.x, bid = blockIdx.x;
  const int b = bid >> 7;
  const int m = (bid & 127) * 32 + (tid >> 4);
  const int cp = (tid >> 2) & 3, h = tid & 3;
  float s[16];
#pragma unroll
  for (int kk = 0; kk < 16; ++kk) s[kk] = 0.f;
#pragma unroll
  for (int gi = 0; gi < 2; ++gi) {
    const int g = cp * 2 + gi;
    const float* pp = psbuf + (size_t)((b * 8 + g) * 4096 + m) * 64 + h;
#pragma unroll
    for (int kk = 0; kk < 16; ++kk) s[kk] += pp[kk * 4];
  }
#pragma unroll
  for (int kk = 0; kk < 16; ++kk) {
    s[kk] += __shfl_xor(s[kk], 4);
    s[kk] += __shfl_xor(s[kk], 8);
    s[kk] *= 0.125f;                       // 1/sqrt(64)
  }
  float mx = s[0];
#pragma unroll
  for (int kk = 1; kk < 16; ++kk) mx = fmaxf(mx, s[kk]);
  float sm = 0.f;
#pragma unroll
  for (int kk = 0; kk < 16; ++kk) { s[kk] = __expf(s[kk] - mx); sm += s[kk]; }
  const float inv = 1.f / sm;
#pragma unroll
  for (int kk = 0; kk < 16; ++kk) s[kk] *= inv;
  if (cp == 0) {
    unsigned short o16[16];
#pragma unroll
    for (int kk = 0; kk < 16; ++kk) o16[kk] = f2bf(s[kk]);
    unsigned short* dst = prob + ((size_t)(b * 4096 + m) * 4 + h) * 16;
    *(uint4*)dst = *(const uint4*)&o16[0];
    *(uint4*)(dst + 8) = *(const uint4*)&o16[8];
  }
#pragma unroll
  for (int kk = 0; kk < 16; ++kk) {        // reduce prob over h lanes for psum
    s[kk] += __shfl_xor(s[kk], 1);
    s[kk] += __shfl_xor(s[kk], 2);
  }
  if (cp == 0 && h == 0) {
    float* dst = psum + ((size_t)b * M_ + m) * 16;
#pragma unroll
    for (int j = 0; j < 4; ++j) {
      f32x4 o = {s[j * 4], s[j * 4 + 1], s[j * 4 + 2], s[j * 4 + 3]};
      *(f32x4*)(dst + j * 4) = o;
    }
  }
}

// ---- pv_part: contiguous value streaming + prob contraction, LDS-collect writeout ------
// grid = 512, 512 threads. prob slab staged to padded LDS (no strided global reads).
__global__ __launch_bounds__(512)
void pv_part(const float* __restrict__ value, const unsigned short* __restrict__ prob,
             unsigned short* __restrict__ pvbuf) {
  __shared__ unsigned short pl[128 * 68];        // [m][h*16+kk], 68-short rows (pad 4)
  __shared__ unsigned short pvt[128 * 132];      // [m][ch-local], padded row 132
  const int tid = threadIdx.x;
  const int bid = blockIdx.x;
  const int cg = bid & 7, msb = (bid >> 3) & 31, b = bid >> 8;
  const int m0 = msb * 128, C0 = cg * 32;
  const int mq = tid >> 2, kq4 = tid & 3;
  // stage prob slab: 16KB contiguous -> padded LDS
  {
    const unsigned short* pb = prob + (size_t)(b * 4096 + m0) * 64;
#pragma unroll
    for (int i = 0; i < 2; ++i) {
      const int g = tid + i * 512;               // uint4 index 0..1023
      const int m = g >> 3, off = g & 7;
      *(uint4*)&pl[m * 68 + off * 8] = *(const uint4*)(pb + m * 64 + off * 8);
    }
  }
  __syncthreads();
  f32x4 pr[4];
#pragma unroll
  for (int h = 0; h < 4; ++h) {
    const uint2 pw = *(const uint2*)&pl[mq * 68 + h * 16 + kq4 * 4];
    pr[h][0] = u2f(pw.x << 16); pr[h][1] = u2f(pw.x & 0xffff0000u);
    pr[h][2] = u2f(pw.y << 16); pr[h][3] = u2f(pw.y & 0xffff0000u);
  }
  const float* vp = value + (size_t)(b * 256 + C0) * 65536 + (size_t)m0 * 16;
  const int moff = mq * 16 + kq4 * 4;
  const bool k0 = (kq4 == 0), k1 = (kq4 == 1), k2 = (kq4 == 2);
#pragma unroll 8
  for (int c = 0; c < 32; ++c) {
    const f32x4 vv = *(const f32x4*)(vp + (size_t)c * 65536 + moff);
    float p0 = vv[0]*pr[0][0] + vv[1]*pr[0][1] + vv[2]*pr[0][2] + vv[3]*pr[0][3];
    float p1 = vv[0]*pr[1][0] + vv[1]*pr[1][1] + vv[2]*pr[1][2] + vv[3]*pr[1][3];
    float p2 = vv[0]*pr[2][0] + vv[1]*pr[2][1] + vv[2]*pr[2][2] + vv[3]*pr[2][3];
    float p3 = vv[0]*pr[3][0] + vv[1]*pr[3][1] + vv[2]*pr[3][2] + vv[3]*pr[3][3];
    p0 += __shfl_xor(p0, 1); p0 += __shfl_xor(p0, 2);
    p1 += __shfl_xor(p1, 1); p1 += __shfl_xor(p1, 2);
    p2 += __shfl_xor(p2, 1); p2 += __shfl_xor(p2, 2);
    p3 += __shfl_xor(p3, 1); p3 += __shfl_xor(p3, 2);
    const float psel = k0 ? p0 : (k1 ? p1 : (k2 ? p2 : p3));
    pvt[mq * 132 + c * 4 + kq4] = f2bf(psel);
  }
  __syncthreads();
  // writeout: pv[b][m][ch=(C0+c)*4+h] bf16, 64B per thread, 256B runs per row
  {
    const int row = tid >> 2, part = tid & 3;
    unsigned short* dst = pvbuf + (size_t)(b * 4096 + m0 + row) * 1024 + C0 * 4 + part * 32;
    const unsigned short* srcl = &pvt[row * 132 + part * 32];
#pragma unroll
    for (int j = 0; j < 4; ++j)
      *(uint4*)(dst + j * 8) = *(const uint4*)(srcl + j * 8);
  }
}

// ---- out_gemm: out[b][o][m] = Wmv × pv + btot ; grid = B*256 (16-col tiles), K=1024 ----
__global__ __launch_bounds__(512)
void out_gemm(const unsigned short* __restrict__ pvbuf, const unsigned short* __restrict__ Wmv,
              const float* __restrict__ btot, float* __restrict__ Out) {
  __shared__ unsigned short Xl[2][16 * 256];
  const int tid = threadIdx.x;
  const int lane = tid & 63, wid = tid >> 6;
  const int b = blockIdx.x >> 8;
  const int m0 = (blockIdx.x & 255) * 16;
  const int scol = tid & 15, sq = tid >> 4;
  const int bcol = lane & 15;
  const int rdk = 16 * (lane >> 4);
  f32x4 acc[2] = {};
  for (int kp = 0; kp < 4; ++kp) {
    {
      const unsigned short* src = pvbuf + ((size_t)(b * M_ + m0 + scol) * 1024 + kp * 256 + sq * 8);
      uint4 v0 = *(const uint4*)src;
      *(uint4*)((char*)Xl[kp & 1] + swz512(scol, sq * 16)) = v0;
    }
    __syncthreads();
    short8 a_cur[2], a_nxt[2];
#pragma unroll
    for (int fi = 0; fi < 2; ++fi)
      a_cur[fi] = *(const short8*)(Wmv + (size_t)((((kp * 8) * 16 + wid * 2 + fi) * 64 + lane) * 8));
#pragma unroll
    for (int kgs = 0; kgs < 8; ++kgs) {
      if (kgs < 7) {
#pragma unroll
        for (int fi = 0; fi < 2; ++fi)
          a_nxt[fi] = *(const short8*)(Wmv + (size_t)((((kp * 8 + kgs + 1) * 16 + wid * 2 + fi) * 64 + lane) * 8));
      }
      short8 bb = *(const short8*)((const char*)Xl[kp & 1] + swz512(bcol, 64 * kgs + rdk));
#pragma unroll
      for (int fi = 0; fi < 2; ++fi)
        acc[fi] = __builtin_amdgcn_mfma_f32_16x16x32_bf16(a_cur[fi], bb, acc[fi], 0, 0, 0);
#pragma unroll
      for (int fi = 0; fi < 2; ++fi) a_cur[fi] = a_nxt[fi];
    }
    if (kp < 3) __syncthreads();
  }
#pragma unroll
  for (int fi = 0; fi < 2; ++fi) {
#pragma unroll
    for (int r = 0; r < 4; ++r) {
      const int o = (wid * 2 + fi) * 16 + (lane >> 4) * 4 + r;
      Out[(size_t)(b * DM_ + o) * M_ + m0 + bcol] = acc[fi][r] + btot[o];
    }
  }
}

extern "C" void kernel_launch(void* const* d_in, const int* in_sizes, int n_in,
                              void* d_out, int out_size, void* d_ws, size_t ws_size,
                              hipStream_t stream) {
  const float* query = (const float*)d_in[0];
  const float* key   = (const float*)d_in[1];
  const float* value = (const float*)d_in[2];
  const float* Wq = (const float*)d_in[3];
  const float* bq = (const float*)d_in[4];
  const float* Wk = (const float*)d_in[5];
  const float* bk = (const float*)d_in[6];  (void)bk;  // folded: softmax-invariant
  const float* Wv = (const float*)d_in[7];
  const float* bv = (const float*)d_in[8];
  const float* Wm = (const float*)d_in[9];
  const float* bm = (const float*)d_in[10];
  float* out  = (float*)d_out;
  float* psum = out + (size_t)B_ * DM_ * M_;   // outputs concatenated: out then prob_sum

  // ---- workspace layout (34.6 MB) ----
  // region0: W2T 512K | Wmv 512K | qb2 4K | btot 1K          (1.05 MB)
  // region1: qW 16.78 MB  (dead after score_part; prob bf16 1 MB aliases its head)
  // region2: ps f32 16.78 MB (dead after softmax_k; pv bf16 16.78 MB aliases it)
  const size_t Wmv_off  = 524288;
  const size_t qb2_off  = 1048576;
  const size_t btot_off = 1052672;
  const size_t qW_off   = 1053696;
  const size_t ps_off   = qW_off + (size_t)B_ * 1024 * M_ * 2;

  unsigned short* W2T   = (unsigned short*)d_ws;
  unsigned short* Wmv   = (unsigned short*)((char*)d_ws + Wmv_off);
  float* qb2            = (float*)((char*)d_ws + qb2_off);
  float* btot           = (float*)((char*)d_ws + btot_off);
  unsigned short* qWbuf = (unsigned short*)((char*)d_ws + qW_off);
  unsigned short* prob  = qWbuf;                                   // alias (qW dead)
  float* psbuf          = (float*)((char*)d_ws + ps_off);
  unsigned short* pvbuf = (unsigned short*)((char*)d_ws + ps_off); // alias (ps dead)

  prep2<<<dim3(1027), dim3(512), 0, stream>>>(Wq, bq, Wk, Wv, bv, Wm, bm, W2T, Wmv, qb2, btot);
  qw_gemm<<<dim3(B_ * 4 * 128), dim3(512), 0, stream>>>(query, W2T, qb2, qWbuf);
  score_part<<<dim3(512), dim3(512), 0, stream>>>(key, qWbuf, psbuf);
  softmax_k<<<dim3(256), dim3(512), 0, stream>>>(psbuf, prob, psum);
  pv_part<<<dim3(512), dim3(512), 0, stream>>>(value, prob, pvbuf);
  out_gemm<<<dim3(B_ * 256), dim3(512), 0, stream>>>(pvbuf, Wmv, btot, out);
}

// Round 9
// 108.074 us; speedup vs baseline: 3.7739x; 1.2462x over previous
//
#include <hip/hip_runtime.h>
#include <stdint.h>

#define DM_ 256
#define H_ 4
#define M_ 4096
#define KN_ 16
#define B_ 2
#define MK_ (M_*KN_)

typedef __attribute__((ext_vector_type(8))) short short8;
typedef __attribute__((ext_vector_type(4))) float f32x4;
typedef __attribute__((ext_vector_type(4))) unsigned short u16x4;

static __device__ __forceinline__ unsigned short f2bf(float x) {
  union { float f; uint32_t u; } v; v.f = x;
  uint32_t u = v.u + (0x7FFFu + ((v.u >> 16) & 1u));  // RNE
  return (unsigned short)(u >> 16);
}
static __device__ __forceinline__ float u2f(uint32_t u) {
  union { uint32_t u; float f; } v; v.u = u; return v.f;
}

// XOR swizzle for [col][k] bf16 tiles (row stride 512 B), bank-floor b128 reads/writes.
static __device__ __forceinline__ int swz512(int col, int kbyte) {
  int f = ((col >> 2) & 7) ^ ((col & 1) << 2);
  return (col << 9) + (kbyte ^ (f << 4));
}

// ---- prep2: weight products, fragment-linear bf16, fused biases ------------------------
__global__ void prep2(const float* __restrict__ Wq, const float* __restrict__ bq,
                      const float* __restrict__ Wk, const float* __restrict__ Wv,
                      const float* __restrict__ bv, const float* __restrict__ Wm,
                      const float* __restrict__ bm,
                      unsigned short* __restrict__ W2T, unsigned short* __restrict__ Wmv,
                      float* __restrict__ qb2, float* __restrict__ btot) {
  int t = blockIdx.x * 512 + threadIdx.x;
  if (t < 262144) {                       // W2T fragment-linear [kstep8][rowblk64][lane][8]
    int j = t & 7, lane = (t >> 3) & 63, rowblk = (t >> 9) & 63, kstep = t >> 15;
    int row = rowblk * 16 + (lane & 15);
    int k = kstep * 32 + (lane >> 4) * 8 + j;
    int h = row >> 8, c = row & 255;
    float v = 0.f;
#pragma unroll 8
    for (int d = 0; d < 64; ++d) v += Wq[(4 * d + h) * 256 + k] * Wk[(4 * d + h) * 256 + c];
    W2T[t] = f2bf(v);
  } else if (t < 524288) {                // Wmv fragment-linear [kstep32][rowblk16][lane][8]
    int e = t - 262144;
    int j = e & 7, lane = (e >> 3) & 63, rowblk = (e >> 9) & 15, kstep = e >> 13;
    int o = rowblk * 16 + (lane & 15);
    int kidx = kstep * 32 + (lane >> 4) * 8 + j;
    int c = kidx >> 2, h = kidx & 3;
    float v = 0.f;
#pragma unroll 8
    for (int d = 0; d < 64; ++d) v += Wm[o * 256 + 4 * d + h] * Wv[(4 * d + h) * 256 + c];
    Wmv[e] = f2bf(v);
  } else if (t < 525312) {
    int r = t - 524288; int h = r >> 8, c = r & 255;
    float v = 0.f;
#pragma unroll 8
    for (int d = 0; d < 64; ++d) v += bq[4 * d + h] * Wk[(4 * d + h) * 256 + c];
    qb2[r] = v;
  } else if (t < 525568) {
    int o = t - 525312;
    float v = bm[o];
#pragma unroll 8
    for (int c2 = 0; c2 < 256; ++c2) v += Wm[o * 256 + c2] * bv[c2];
    btot[o] = v;
  }
}

// ---- qw_gemm: qW[b][r=h*256+c][m] (bf16) = W2T × query + qb2 ; grid = B*4rt*128mt ------
__global__ __launch_bounds__(512)
void qw_gemm(const float* __restrict__ query, const unsigned short* __restrict__ W2T,
             const float* __restrict__ qb2, unsigned short* __restrict__ qWbuf) {
  __shared__ unsigned short Xl[32 * 256];
  const int tid = threadIdx.x;
  const int lane = tid & 63, wid = tid >> 6;
  const int wr = wid >> 1, wc = wid & 1;
  const int mt = blockIdx.x & 127;
  const int rt = (blockIdx.x >> 7) & 3;
  const int b = blockIdx.x >> 9;
  const int m0 = mt * 32;
  const float* Xb = query + (size_t)b * DM_ * M_ + m0;
  const int c4 = 4 * (tid & 7);
  const int ch0 = 4 * (tid >> 3);
  float4 f[4];
#pragma unroll
  for (int i = 0; i < 4; ++i) f[i] = *(const float4*)(Xb + (size_t)(ch0 + i) * M_ + c4);
#pragma unroll
  for (int j = 0; j < 4; ++j) {
    u16x4 u = { f2bf(((const float*)&f[0])[j]), f2bf(((const float*)&f[1])[j]),
                f2bf(((const float*)&f[2])[j]), f2bf(((const float*)&f[3])[j]) };
    *(u16x4*)((char*)Xl + swz512(c4 + j, 2 * ch0)) = u;
  }
  __syncthreads();
  f32x4 acc[4] = {};
  const int bcol = wc * 16 + (lane & 15);
  const int rdk = 16 * (lane >> 4);
  short8 a_cur[4], a_nxt[4];
#pragma unroll
  for (int fi = 0; fi < 4; ++fi)
    a_cur[fi] = *(const short8*)(W2T + (size_t)(((rt * 16 + wr * 4 + fi) * 64 + lane) * 8));
#pragma unroll
  for (int kgs = 0; kgs < 8; ++kgs) {
    if (kgs < 7) {
#pragma unroll
      for (int fi = 0; fi < 4; ++fi)
        a_nxt[fi] = *(const short8*)(W2T + (size_t)((((kgs + 1) * 64 + rt * 16 + wr * 4 + fi) * 64 + lane) * 8));
    }
    short8 bb = *(const short8*)((const char*)Xl + swz512(bcol, 64 * kgs + rdk));
#pragma unroll
    for (int fi = 0; fi < 4; ++fi)
      acc[fi] = __builtin_amdgcn_mfma_f32_16x16x32_bf16(a_cur[fi], bb, acc[fi], 0, 0, 0);
#pragma unroll
    for (int fi = 0; fi < 4; ++fi) a_cur[fi] = a_nxt[fi];
  }
#pragma unroll
  for (int fi = 0; fi < 4; ++fi) {
#pragma unroll
    for (int r = 0; r < 4; ++r) {
      const int rr = rt * 256 + wr * 64 + fi * 16 + (lane >> 4) * 4 + r;
      qWbuf[(size_t)(b * 1024 + rr) * M_ + m0 + bcol] = f2bf(acc[fi][r] + qb2[rr]);
    }
  }
}

// ---- fused_attn: scores + softmax + psum + PV + merge-GEMM, single pass over K and V ---
// grid = B*256 = 512 blocks (XCD-chunked), 512 threads. Block: m-slab [mt*16, +16), all
// 256 channels. tid = mq(4b)<<5 | cs(3b)<<2 | kq(2b).
// LDS (32 KB, aliased): qsl[c 256][slot 16][h 4] bf16 during score; pvt[m' 16][k 1024]
// bf16 (XOR-swizzled) during PV + merge.
__global__ __launch_bounds__(512, 4)
void fused_attn(const float* __restrict__ key, const float* __restrict__ value,
                const unsigned short* __restrict__ qW, const unsigned short* __restrict__ Wmv,
                const float* __restrict__ btot, float* __restrict__ out,
                float* __restrict__ psum) {
  __shared__ unsigned short sh[16384];   // 32 KB
  const int tid = threadIdx.x;
  const int lane = tid & 63;
  const int vb = (blockIdx.x & 7) * 64 + (blockIdx.x >> 3);   // 512 = 8 XCD x 64
  const int b = vb >> 8;
  const int mt = vb & 255;
  const int m0 = mt * 16;
  // ---- stage qW slab: [c][slot=(mq+c)&15][h], rotation kills bank aliasing ----
  {
    const int c = tid & 255, hh = (tid >> 8) << 1;   // hh in {0,2}
    uint4 rv[2][2];
#pragma unroll
    for (int h2 = 0; h2 < 2; ++h2) {
      const unsigned short* src = qW + ((size_t)(b * 1024 + (hh + h2) * 256 + c)) * M_ + m0;
      rv[h2][0] = *(const uint4*)(src);
      rv[h2][1] = *(const uint4*)(src + 8);
    }
    const unsigned short* rs = (const unsigned short*)rv;   // rs[h2*16 + q]
#pragma unroll
    for (int q = 0; q < 16; ++q) {
      const int slot = (q + c) & 15;
      const uint32_t o = (uint32_t)rs[q] | ((uint32_t)rs[16 + q] << 16);
      *(uint32_t*)&sh[c * 64 + slot * 4 + hh] = o;
    }
  }
  __syncthreads();
  const int mq = tid >> 5;                 // 0..15
  const int cs = (tid >> 2) & 7;           // 0..7
  const int kq = tid & 3;                  // 0..3
  const float* kp = key + (size_t)(b * 256) * 65536 + (size_t)m0 * 16;
  const float* vp = value + (size_t)(b * 256) * 65536 + (size_t)m0 * 16;
  const int moff = mq * 16 + kq * 4;
  // ---- score pass: all 256 channels of key, contiguous ----
  f32x4 ps0 = {}, ps1 = {}, ps2 = {}, ps3 = {};
#pragma unroll 2
  for (int cc = 0; cc < 8; ++cc) {
#pragma unroll
    for (int i = 0; i < 4; ++i) {
      const int c = cc * 32 + cs * 4 + i;
      const f32x4 kv = *(const f32x4*)(kp + (size_t)c * 65536 + moff);
      const int slot = (mq + c) & 15;
      const uint2 qv = *(const uint2*)&sh[c * 64 + slot * 4];
      ps0 += kv * u2f(qv.x << 16);
      ps1 += kv * u2f(qv.x & 0xffff0000u);
      ps2 += kv * u2f(qv.y << 16);
      ps3 += kv * u2f(qv.y & 0xffff0000u);
    }
  }
  // reduce over cs (lane bits 2..4)
#pragma unroll
  for (int j = 0; j < 4; ++j) {
    ps0[j] += __shfl_xor(ps0[j], 4); ps0[j] += __shfl_xor(ps0[j], 8); ps0[j] += __shfl_xor(ps0[j], 16);
    ps1[j] += __shfl_xor(ps1[j], 4); ps1[j] += __shfl_xor(ps1[j], 8); ps1[j] += __shfl_xor(ps1[j], 16);
    ps2[j] += __shfl_xor(ps2[j], 4); ps2[j] += __shfl_xor(ps2[j], 8); ps2[j] += __shfl_xor(ps2[j], 16);
    ps3[j] += __shfl_xor(ps3[j], 4); ps3[j] += __shfl_xor(ps3[j], 8); ps3[j] += __shfl_xor(ps3[j], 16);
  }
  // ---- softmax per (m, h) over 16 kk: local 4 + xor over kq (lane bits 0..1) ----
  f32x4 pr0, pr1, pr2, pr3;
#define SOFT(ps, pr) { \
    f32x4 s = ps * 0.125f; \
    float mx = fmaxf(fmaxf(s[0], s[1]), fmaxf(s[2], s[3])); \
    mx = fmaxf(mx, __shfl_xor(mx, 1)); mx = fmaxf(mx, __shfl_xor(mx, 2)); \
    f32x4 e; \
    e[0] = __expf(s[0] - mx); e[1] = __expf(s[1] - mx); \
    e[2] = __expf(s[2] - mx); e[3] = __expf(s[3] - mx); \
    float sm = e[0] + e[1] + e[2] + e[3]; \
    sm += __shfl_xor(sm, 1); sm += __shfl_xor(sm, 2); \
    const float inv = 1.f / sm; \
    pr[0] = e[0] * inv; pr[1] = e[1] * inv; pr[2] = e[2] * inv; pr[3] = e[3] * inv; \
  }
  SOFT(ps0, pr0) SOFT(ps1, pr1) SOFT(ps2, pr2) SOFT(ps3, pr3)
#undef SOFT
  // psum[b][m][kk] = sum_h prob
  if (cs == 0) {
    f32x4 pp = pr0 + pr1 + pr2 + pr3;
    *(f32x4*)(psum + ((size_t)b * M_ + m0 + mq) * KN_ + kq * 4) = pp;
  }
  __syncthreads();                          // qsl dead; pvt takes over the LDS
  // ---- PV pass: all 256 channels of value, contiguous; pvt[m'][k=c*4+h] swizzled ----
#pragma unroll 2
  for (int cc = 0; cc < 8; ++cc) {
#pragma unroll
    for (int i = 0; i < 4; ++i) {
      const int c = cc * 32 + cs * 4 + i;
      const f32x4 vv = *(const f32x4*)(vp + (size_t)c * 65536 + moff);
      float p0 = vv[0] * pr0[0] + vv[1] * pr0[1] + vv[2] * pr0[2] + vv[3] * pr0[3];
      float p1 = vv[0] * pr1[0] + vv[1] * pr1[1] + vv[2] * pr1[2] + vv[3] * pr1[3];
      float p2 = vv[0] * pr2[0] + vv[1] * pr2[1] + vv[2] * pr2[2] + vv[3] * pr2[3];
      float p3 = vv[0] * pr3[0] + vv[1] * pr3[1] + vv[2] * pr3[2] + vv[3] * pr3[3];
      p0 += __shfl_xor(p0, 1); p0 += __shfl_xor(p0, 2);
      p1 += __shfl_xor(p1, 1); p1 += __shfl_xor(p1, 2);
      p2 += __shfl_xor(p2, 1); p2 += __shfl_xor(p2, 2);
      p3 += __shfl_xor(p3, 1); p3 += __shfl_xor(p3, 2);
      if (kq == 0) {
        uint2 o;
        o.x = (uint32_t)f2bf(p0) | ((uint32_t)f2bf(p1) << 16);
        o.y = (uint32_t)f2bf(p2) | ((uint32_t)f2bf(p3) << 16);
        *(uint2*)((char*)sh + ((mq * 2048 + c * 8) ^ ((mq & 7) << 4))) = o;
      }
    }
  }
  __syncthreads();
  // ---- merge GEMM: out[o][m'] = Wmv(256x1024) x pvt(1024x16) + btot ----
  {
    const int wid = tid >> 6;               // 0..7, rows wid*32..+31
    const int bcol = lane & 15;             // m'
    const int kgrp = lane >> 4;             // 0..3
    f32x4 acc0 = {}, acc1 = {};
    for (int kgs = 0; kgs < 32; ++kgs) {
      const int byte = (bcol * 2048 + kgs * 64 + kgrp * 16) ^ ((bcol & 7) << 4);
      const short8 bb = *(const short8*)((const char*)sh + byte);
      const short8 a0 = *(const short8*)(Wmv + (size_t)(((kgs * 16 + wid * 2 + 0) * 64 + lane) * 8));
      const short8 a1 = *(const short8*)(Wmv + (size_t)(((kgs * 16 + wid * 2 + 1) * 64 + lane) * 8));
      acc0 = __builtin_amdgcn_mfma_f32_16x16x32_bf16(a0, bb, acc0, 0, 0, 0);
      acc1 = __builtin_amdgcn_mfma_f32_16x16x32_bf16(a1, bb, acc1, 0, 0, 0);
    }
#pragma unroll
    for (int r = 0; r < 4; ++r) {
      const int o0 = (wid * 2 + 0) * 16 + kgrp * 4 + r;
      const int o1 = (wid * 2 + 1) * 16 + kgrp * 4 + r;
      out[((size_t)(b * DM_ + o0)) * M_ + m0 + bcol] = acc0[r] + btot[o0];
      out[((size_t)(b * DM_ + o1)) * M_ + m0 + bcol] = acc1[r] + btot[o1];
    }
  }
}

extern "C" void kernel_launch(void* const* d_in, const int* in_sizes, int n_in,
                              void* d_out, int out_size, void* d_ws, size_t ws_size,
                              hipStream_t stream) {
  const float* query = (const float*)d_in[0];
  const float* key   = (const float*)d_in[1];
  const float* value = (const float*)d_in[2];
  const float* Wq = (const float*)d_in[3];
  const float* bq = (const float*)d_in[4];
  const float* Wk = (const float*)d_in[5];
  const float* bk = (const float*)d_in[6];  (void)bk;  // folded: softmax-invariant
  const float* Wv = (const float*)d_in[7];
  const float* bv = (const float*)d_in[8];
  const float* Wm = (const float*)d_in[9];
  const float* bm = (const float*)d_in[10];
  float* out  = (float*)d_out;
  float* psum = out + (size_t)B_ * DM_ * M_;   // outputs concatenated: out then prob_sum

  // ---- workspace layout (17.8 MB) ----
  const size_t Wmv_off  = 524288;
  const size_t qb2_off  = 1048576;
  const size_t btot_off = 1052672;
  const size_t qW_off   = 1053696;             // qW: 16.78 MB bf16

  unsigned short* W2T   = (unsigned short*)d_ws;
  unsigned short* Wmv   = (unsigned short*)((char*)d_ws + Wmv_off);
  float* qb2            = (float*)((char*)d_ws + qb2_off);
  float* btot           = (float*)((char*)d_ws + btot_off);
  unsigned short* qWbuf = (unsigned short*)((char*)d_ws + qW_off);

  prep2<<<dim3(1027), dim3(512), 0, stream>>>(Wq, bq, Wk, Wv, bv, Wm, bm, W2T, Wmv, qb2, btot);
  qw_gemm<<<dim3(B_ * 4 * 128), dim3(512), 0, stream>>>(query, W2T, qb2, qWbuf);
  fused_attn<<<dim3(512), dim3(512), 0, stream>>>(key, value, qWbuf, Wmv, btot, out, psum);
}

// Round 10
// 104.912 us; speedup vs baseline: 3.8877x; 1.0301x over previous
//
#include <hip/hip_runtime.h>
#include <stdint.h>

#define DM_ 256
#define H_ 4
#define M_ 4096
#define KN_ 16
#define B_ 2
#define MK_ (M_*KN_)

typedef __attribute__((ext_vector_type(8))) short short8;
typedef __attribute__((ext_vector_type(4))) float f32x4;
typedef __attribute__((ext_vector_type(4))) unsigned short u16x4;

static __device__ __forceinline__ unsigned short f2bf(float x) {
  union { float f; uint32_t u; } v; v.f = x;
  uint32_t u = v.u + (0x7FFFu + ((v.u >> 16) & 1u));  // RNE
  return (unsigned short)(u >> 16);
}
static __device__ __forceinline__ float u2f(uint32_t u) {
  union { uint32_t u; float f; } v; v.u = u; return v.f;
}

// XOR swizzle for [col][k] bf16 tiles (row stride 512 B), bank-floor b128 reads/writes.
static __device__ __forceinline__ int swz512(int col, int kbyte) {
  int f = ((col >> 2) & 7) ^ ((col & 1) << 2);
  return (col << 9) + (kbyte ^ (f << 4));
}

// ---- prep2: weight products, fragment-linear bf16, fused biases ------------------------
__global__ void prep2(const float* __restrict__ Wq, const float* __restrict__ bq,
                      const float* __restrict__ Wk, const float* __restrict__ Wv,
                      const float* __restrict__ bv, const float* __restrict__ Wm,
                      const float* __restrict__ bm,
                      unsigned short* __restrict__ W2T, unsigned short* __restrict__ Wmv,
                      float* __restrict__ qb2, float* __restrict__ btot) {
  int t = blockIdx.x * 512 + threadIdx.x;
  if (t < 262144) {                       // W2T fragment-linear [kstep8][rowblk64][lane][8]
    int j = t & 7, lane = (t >> 3) & 63, rowblk = (t >> 9) & 63, kstep = t >> 15;
    int row = rowblk * 16 + (lane & 15);
    int k = kstep * 32 + (lane >> 4) * 8 + j;
    int h = row >> 8, c = row & 255;
    float v = 0.f;
#pragma unroll 8
    for (int d = 0; d < 64; ++d) v += Wq[(4 * d + h) * 256 + k] * Wk[(4 * d + h) * 256 + c];
    W2T[t] = f2bf(v);
  } else if (t < 524288) {                // Wmv fragment-linear [kstep32][rowblk16][lane][8]
    int e = t - 262144;
    int j = e & 7, lane = (e >> 3) & 63, rowblk = (e >> 9) & 15, kstep = e >> 13;
    int o = rowblk * 16 + (lane & 15);
    int kidx = kstep * 32 + (lane >> 4) * 8 + j;
    int c = kidx >> 2, h = kidx & 3;
    float v = 0.f;
#pragma unroll 8
    for (int d = 0; d < 64; ++d) v += Wm[o * 256 + 4 * d + h] * Wv[(4 * d + h) * 256 + c];
    Wmv[e] = f2bf(v);
  } else if (t < 525312) {
    int r = t - 524288; int h = r >> 8, c = r & 255;
    float v = 0.f;
#pragma unroll 8
    for (int d = 0; d < 64; ++d) v += bq[4 * d + h] * Wk[(4 * d + h) * 256 + c];
    qb2[r] = v;
  } else if (t < 525568) {
    int o = t - 525312;
    float v = bm[o];
#pragma unroll 8
    for (int c2 = 0; c2 < 256; ++c2) v += Wm[o * 256 + c2] * bv[c2];
    btot[o] = v;
  }
}

// ---- qw_gemm: qW[b][r=h*256+c][m] (bf16) = W2T × query + qb2 ; grid = B*4rt*128mt ------
__global__ __launch_bounds__(512)
void qw_gemm(const float* __restrict__ query, const unsigned short* __restrict__ W2T,
             const float* __restrict__ qb2, unsigned short* __restrict__ qWbuf) {
  __shared__ unsigned short Xl[32 * 256];
  const int tid = threadIdx.x;
  const int lane = tid & 63, wid = tid >> 6;
  const int wr = wid >> 1, wc = wid & 1;
  const int mt = blockIdx.x & 127;
  const int rt = (blockIdx.x >> 7) & 3;
  const int b = blockIdx.x >> 9;
  const int m0 = mt * 32;
  const float* Xb = query + (size_t)b * DM_ * M_ + m0;
  const int c4 = 4 * (tid & 7);
  const int ch0 = 4 * (tid >> 3);
  float4 f[4];
#pragma unroll
  for (int i = 0; i < 4; ++i) f[i] = *(const float4*)(Xb + (size_t)(ch0 + i) * M_ + c4);
#pragma unroll
  for (int j = 0; j < 4; ++j) {
    u16x4 u = { f2bf(((const float*)&f[0])[j]), f2bf(((const float*)&f[1])[j]),
                f2bf(((const float*)&f[2])[j]), f2bf(((const float*)&f[3])[j]) };
    *(u16x4*)((char*)Xl + swz512(c4 + j, 2 * ch0)) = u;
  }
  __syncthreads();
  f32x4 acc[4] = {};
  const int bcol = wc * 16 + (lane & 15);
  const int rdk = 16 * (lane >> 4);
  short8 a_cur[4], a_nxt[4];
#pragma unroll
  for (int fi = 0; fi < 4; ++fi)
    a_cur[fi] = *(const short8*)(W2T + (size_t)(((rt * 16 + wr * 4 + fi) * 64 + lane) * 8));
#pragma unroll
  for (int kgs = 0; kgs < 8; ++kgs) {
    if (kgs < 7) {
#pragma unroll
      for (int fi = 0; fi < 4; ++fi)
        a_nxt[fi] = *(const short8*)(W2T + (size_t)((((kgs + 1) * 64 + rt * 16 + wr * 4 + fi) * 64 + lane) * 8));
    }
    short8 bb = *(const short8*)((const char*)Xl + swz512(bcol, 64 * kgs + rdk));
#pragma unroll
    for (int fi = 0; fi < 4; ++fi)
      acc[fi] = __builtin_amdgcn_mfma_f32_16x16x32_bf16(a_cur[fi], bb, acc[fi], 0, 0, 0);
#pragma unroll
    for (int fi = 0; fi < 4; ++fi) a_cur[fi] = a_nxt[fi];
  }
#pragma unroll
  for (int fi = 0; fi < 4; ++fi) {
#pragma unroll
    for (int r = 0; r < 4; ++r) {
      const int rr = rt * 256 + wr * 64 + fi * 16 + (lane >> 4) * 4 + r;
      qWbuf[(size_t)(b * 1024 + rr) * M_ + m0 + bcol] = f2bf(acc[fi][r] + qb2[rr]);
    }
  }
}

// ---- fused_attn: scores + softmax + psum + PV + merge-GEMM, single pass over K and V ---
// grid = B*256 = 512 blocks (XCD-chunked), 1024 threads (16 waves) -> 2 blocks/CU =
// 32 waves/CU = 100% occupancy. Block: m-slab [mt*16,+16), all 256 channels.
// tid = mq(4b)<<6 | cs(4b)<<2 | kq(2b); mq == wave id, so cs/kq reductions are in-wave.
// LDS (32 KB, aliased): qsl[c 256][slot 16][h 4] bf16 (rotation-swizzled) during score;
// pvt[m' 16][k 1024] bf16 (XOR-swizzled) during PV + merge GEMM.
__global__ __launch_bounds__(1024, 8)
void fused_attn(const float* __restrict__ key, const float* __restrict__ value,
                const unsigned short* __restrict__ qW, const unsigned short* __restrict__ Wmv,
                const float* __restrict__ btot, float* __restrict__ out,
                float* __restrict__ psum) {
  __shared__ unsigned short sh[16384];   // 32 KB
  const int tid = threadIdx.x;
  const int lane = tid & 63;
  const int vb = (blockIdx.x & 7) * 64 + (blockIdx.x >> 3);   // 512 = 8 XCD x 64
  const int b = vb >> 8;
  const int m0 = (vb & 255) * 16;
  // ---- stage qW slab: one (h,c) row per thread; [c][slot=(q+c)&15][h] rotation ----
  {
    const int c = tid & 255, h = tid >> 8;   // h 0..3
    const unsigned short* src = qW + ((size_t)(b * 1024 + h * 256 + c)) * M_ + m0;
    uint4 rv[2];
    rv[0] = *(const uint4*)(src);
    rv[1] = *(const uint4*)(src + 8);
    const unsigned short* rs = (const unsigned short*)rv;   // rs[q], q = m-local
#pragma unroll
    for (int q = 0; q < 16; ++q) {
      const int slot = (q + c) & 15;
      sh[c * 64 + slot * 4 + h] = rs[q];
    }
  }
  __syncthreads();
  const int mq = tid >> 6;                 // 0..15 (wave id)
  const int cs = (tid >> 2) & 15;          // 0..15
  const int kq = tid & 3;                  // 0..3
  const float* kp = key + (size_t)(b * 256) * 65536 + (size_t)m0 * 16;
  const float* vp = value + (size_t)(b * 256) * 65536 + (size_t)m0 * 16;
  const int moff = mq * 16 + kq * 4;
  // ---- score pass: all 256 channels of key, 16 per thread ----
  f32x4 ps0 = {}, ps1 = {}, ps2 = {}, ps3 = {};
#pragma unroll 4
  for (int i = 0; i < 16; ++i) {
    const int c = i * 16 + cs;
    const f32x4 kv = *(const f32x4*)(kp + (size_t)c * 65536 + moff);
    const int slot = (mq + c) & 15;
    const uint2 qv = *(const uint2*)&sh[c * 64 + slot * 4];
    ps0 += kv * u2f(qv.x << 16);
    ps1 += kv * u2f(qv.x & 0xffff0000u);
    ps2 += kv * u2f(qv.y << 16);
    ps3 += kv * u2f(qv.y & 0xffff0000u);
  }
  // reduce over cs (lane bits 2..5)
#pragma unroll
  for (int j = 0; j < 4; ++j) {
    ps0[j] += __shfl_xor(ps0[j], 4); ps0[j] += __shfl_xor(ps0[j], 8);
    ps0[j] += __shfl_xor(ps0[j], 16); ps0[j] += __shfl_xor(ps0[j], 32);
    ps1[j] += __shfl_xor(ps1[j], 4); ps1[j] += __shfl_xor(ps1[j], 8);
    ps1[j] += __shfl_xor(ps1[j], 16); ps1[j] += __shfl_xor(ps1[j], 32);
    ps2[j] += __shfl_xor(ps2[j], 4); ps2[j] += __shfl_xor(ps2[j], 8);
    ps2[j] += __shfl_xor(ps2[j], 16); ps2[j] += __shfl_xor(ps2[j], 32);
    ps3[j] += __shfl_xor(ps3[j], 4); ps3[j] += __shfl_xor(ps3[j], 8);
    ps3[j] += __shfl_xor(ps3[j], 16); ps3[j] += __shfl_xor(ps3[j], 32);
  }
  // ---- softmax per (m, h) over 16 kk: local 4 + xor over kq (lane bits 0..1) ----
  f32x4 pr0, pr1, pr2, pr3;
#define SOFT(ps, pr) { \
    f32x4 s = ps * 0.125f; \
    float mx = fmaxf(fmaxf(s[0], s[1]), fmaxf(s[2], s[3])); \
    mx = fmaxf(mx, __shfl_xor(mx, 1)); mx = fmaxf(mx, __shfl_xor(mx, 2)); \
    f32x4 e; \
    e[0] = __expf(s[0] - mx); e[1] = __expf(s[1] - mx); \
    e[2] = __expf(s[2] - mx); e[3] = __expf(s[3] - mx); \
    float sm = e[0] + e[1] + e[2] + e[3]; \
    sm += __shfl_xor(sm, 1); sm += __shfl_xor(sm, 2); \
    const float inv = 1.f / sm; \
    pr[0] = e[0] * inv; pr[1] = e[1] * inv; pr[2] = e[2] * inv; pr[3] = e[3] * inv; \
  }
  SOFT(ps0, pr0) SOFT(ps1, pr1) SOFT(ps2, pr2) SOFT(ps3, pr3)
#undef SOFT
  // psum[b][m][kk] = sum_h prob
  if (cs == 0) {
    f32x4 pp = pr0 + pr1 + pr2 + pr3;
    *(f32x4*)(psum + ((size_t)b * M_ + m0 + mq) * KN_ + kq * 4) = pp;
  }
  __syncthreads();                          // qsl dead; pvt takes over the LDS
  // ---- PV pass: all 256 channels of value; pvt[m'][k=c*4+h] XOR-swizzled ----
#pragma unroll 4
  for (int i = 0; i < 16; ++i) {
    const int c = i * 16 + cs;
    const f32x4 vv = *(const f32x4*)(vp + (size_t)c * 65536 + moff);
    float p0 = vv[0] * pr0[0] + vv[1] * pr0[1] + vv[2] * pr0[2] + vv[3] * pr0[3];
    float p1 = vv[0] * pr1[0] + vv[1] * pr1[1] + vv[2] * pr1[2] + vv[3] * pr1[3];
    float p2 = vv[0] * pr2[0] + vv[1] * pr2[1] + vv[2] * pr2[2] + vv[3] * pr2[3];
    float p3 = vv[0] * pr3[0] + vv[1] * pr3[1] + vv[2] * pr3[2] + vv[3] * pr3[3];
    p0 += __shfl_xor(p0, 1); p0 += __shfl_xor(p0, 2);
    p1 += __shfl_xor(p1, 1); p1 += __shfl_xor(p1, 2);
    p2 += __shfl_xor(p2, 1); p2 += __shfl_xor(p2, 2);
    p3 += __shfl_xor(p3, 1); p3 += __shfl_xor(p3, 2);
    if (kq == 0) {
      uint2 o;
      o.x = (uint32_t)f2bf(p0) | ((uint32_t)f2bf(p1) << 16);
      o.y = (uint32_t)f2bf(p2) | ((uint32_t)f2bf(p3) << 16);
      *(uint2*)((char*)sh + ((mq * 2048 + c * 8) ^ ((mq & 7) << 4))) = o;
    }
  }
  __syncthreads();
  // ---- merge GEMM: out[o][m'] = Wmv(256x1024) x pvt(1024x16) + btot ----
  {
    const int wid = tid >> 6;               // 0..15: A-row-block wid (rows wid*16..+15)
    const int bcol = lane & 15;             // m'
    const int kgrp = lane >> 4;             // 0..3
    f32x4 acc = {};
    for (int kgs = 0; kgs < 32; ++kgs) {
      const int byte = (bcol * 2048 + kgs * 64 + kgrp * 16) ^ ((bcol & 7) << 4);
      const short8 bb = *(const short8*)((const char*)sh + byte);
      const short8 a0 = *(const short8*)(Wmv + (size_t)(((kgs * 16 + wid) * 64 + lane) * 8));
      acc = __builtin_amdgcn_mfma_f32_16x16x32_bf16(a0, bb, acc, 0, 0, 0);
    }
#pragma unroll
    for (int r = 0; r < 4; ++r) {
      const int o = wid * 16 + kgrp * 4 + r;
      out[((size_t)(b * DM_ + o)) * M_ + m0 + bcol] = acc[r] + btot[o];
    }
  }
}

extern "C" void kernel_launch(void* const* d_in, const int* in_sizes, int n_in,
                              void* d_out, int out_size, void* d_ws, size_t ws_size,
                              hipStream_t stream) {
  const float* query = (const float*)d_in[0];
  const float* key   = (const float*)d_in[1];
  const float* value = (const float*)d_in[2];
  const float* Wq = (const float*)d_in[3];
  const float* bq = (const float*)d_in[4];
  const float* Wk = (const float*)d_in[5];
  const float* bk = (const float*)d_in[6];  (void)bk;  // folded: softmax-invariant
  const float* Wv = (const float*)d_in[7];
  const float* bv = (const float*)d_in[8];
  const float* Wm = (const float*)d_in[9];
  const float* bm = (const float*)d_in[10];
  float* out  = (float*)d_out;
  float* psum = out + (size_t)B_ * DM_ * M_;   // outputs concatenated: out then prob_sum

  // ---- workspace layout (17.8 MB) ----
  const size_t Wmv_off  = 524288;
  const size_t qb2_off  = 1048576;
  const size_t btot_off = 1052672;
  const size_t qW_off   = 1053696;             // qW: 16.78 MB bf16

  unsigned short* W2T   = (unsigned short*)d_ws;
  unsigned short* Wmv   = (unsigned short*)((char*)d_ws + Wmv_off);
  float* qb2            = (float*)((char*)d_ws + qb2_off);
  float* btot           = (float*)((char*)d_ws + btot_off);
  unsigned short* qWbuf = (unsigned short*)((char*)d_ws + qW_off);

  prep2<<<dim3(1027), dim3(512), 0, stream>>>(Wq, bq, Wk, Wv, bv, Wm, bm, W2T, Wmv, qb2, btot);
  qw_gemm<<<dim3(B_ * 4 * 128), dim3(512), 0, stream>>>(query, W2T, qb2, qWbuf);
  fused_attn<<<dim3(512), dim3(1024), 0, stream>>>(key, value, qWbuf, Wmv, btot, out, psum);
}

// Round 11
// 103.311 us; speedup vs baseline: 3.9479x; 1.0155x over previous
//
#include <hip/hip_runtime.h>
#include <stdint.h>

#define DM_ 256
#define H_ 4
#define M_ 4096
#define KN_ 16
#define B_ 2
#define MK_ (M_*KN_)

typedef __attribute__((ext_vector_type(8))) short short8;
typedef __attribute__((ext_vector_type(4))) float f32x4;
typedef __attribute__((ext_vector_type(4))) unsigned short u16x4;

static __device__ __forceinline__ unsigned short f2bf(float x) {
  union { float f; uint32_t u; } v; v.f = x;
  uint32_t u = v.u + (0x7FFFu + ((v.u >> 16) & 1u));  // RNE
  return (unsigned short)(u >> 16);
}
static __device__ __forceinline__ float u2f(uint32_t u) {
  union { uint32_t u; float f; } v; v.u = u; return v.f;
}

// XOR swizzle for [col][k] bf16 tiles (row stride 512 B), bank-floor b128 reads/writes.
static __device__ __forceinline__ int swz512(int col, int kbyte) {
  int f = ((col >> 2) & 7) ^ ((col & 1) << 2);
  return (col << 9) + (kbyte ^ (f << 4));
}

// ---- prep2: weight products, fragment-linear bf16, fused biases ------------------------
__global__ void prep2(const float* __restrict__ Wq, const float* __restrict__ bq,
                      const float* __restrict__ Wk, const float* __restrict__ Wv,
                      const float* __restrict__ bv, const float* __restrict__ Wm,
                      const float* __restrict__ bm,
                      unsigned short* __restrict__ W2T, unsigned short* __restrict__ Wmv,
                      float* __restrict__ qb2, float* __restrict__ btot) {
  int t = blockIdx.x * 512 + threadIdx.x;
  if (t < 262144) {                       // W2T fragment-linear [kstep8][rowblk64][lane][8]
    int j = t & 7, lane = (t >> 3) & 63, rowblk = (t >> 9) & 63, kstep = t >> 15;
    int row = rowblk * 16 + (lane & 15);
    int k = kstep * 32 + (lane >> 4) * 8 + j;
    int h = row >> 8, c = row & 255;
    float v = 0.f;
#pragma unroll 8
    for (int d = 0; d < 64; ++d) v += Wq[(4 * d + h) * 256 + k] * Wk[(4 * d + h) * 256 + c];
    W2T[t] = f2bf(v);
  } else if (t < 524288) {                // Wmv fragment-linear [kstep32][rowblk16][lane][8]
    int e = t - 262144;
    int j = e & 7, lane = (e >> 3) & 63, rowblk = (e >> 9) & 15, kstep = e >> 13;
    int o = rowblk * 16 + (lane & 15);
    int kidx = kstep * 32 + (lane >> 4) * 8 + j;
    int c = kidx >> 2, h = kidx & 3;
    float v = 0.f;
#pragma unroll 8
    for (int d = 0; d < 64; ++d) v += Wm[o * 256 + 4 * d + h] * Wv[(4 * d + h) * 256 + c];
    Wmv[e] = f2bf(v);
  } else if (t < 525312) {
    int r = t - 524288; int h = r >> 8, c = r & 255;
    float v = 0.f;
#pragma unroll 8
    for (int d = 0; d < 64; ++d) v += bq[4 * d + h] * Wk[(4 * d + h) * 256 + c];
    qb2[r] = v;
  } else if (t < 525568) {
    int o = t - 525312;
    float v = bm[o];
#pragma unroll 8
    for (int c2 = 0; c2 < 256; ++c2) v += Wm[o * 256 + c2] * bv[c2];
    btot[o] = v;
  }
}

// ---- qw_gemm: qW[b][r=h*256+c][m] (bf16) = W2T × query + qb2 ; grid = B*4rt*128mt ------
__global__ __launch_bounds__(512)
void qw_gemm(const float* __restrict__ query, const unsigned short* __restrict__ W2T,
             const float* __restrict__ qb2, unsigned short* __restrict__ qWbuf) {
  __shared__ unsigned short Xl[32 * 256];
  const int tid = threadIdx.x;
  const int lane = tid & 63, wid = tid >> 6;
  const int wr = wid >> 1, wc = wid & 1;
  const int mt = blockIdx.x & 127;
  const int rt = (blockIdx.x >> 7) & 3;
  const int b = blockIdx.x >> 9;
  const int m0 = mt * 32;
  const float* Xb = query + (size_t)b * DM_ * M_ + m0;
  const int c4 = 4 * (tid & 7);
  const int ch0 = 4 * (tid >> 3);
  float4 f[4];
#pragma unroll
  for (int i = 0; i < 4; ++i) f[i] = *(const float4*)(Xb + (size_t)(ch0 + i) * M_ + c4);
#pragma unroll
  for (int j = 0; j < 4; ++j) {
    u16x4 u = { f2bf(((const float*)&f[0])[j]), f2bf(((const float*)&f[1])[j]),
                f2bf(((const float*)&f[2])[j]), f2bf(((const float*)&f[3])[j]) };
    *(u16x4*)((char*)Xl + swz512(c4 + j, 2 * ch0)) = u;
  }
  __syncthreads();
  f32x4 acc[4] = {};
  const int bcol = wc * 16 + (lane & 15);
  const int rdk = 16 * (lane >> 4);
  short8 a_cur[4], a_nxt[4];
#pragma unroll
  for (int fi = 0; fi < 4; ++fi)
    a_cur[fi] = *(const short8*)(W2T + (size_t)(((rt * 16 + wr * 4 + fi) * 64 + lane) * 8));
#pragma unroll
  for (int kgs = 0; kgs < 8; ++kgs) {
    if (kgs < 7) {
#pragma unroll
      for (int fi = 0; fi < 4; ++fi)
        a_nxt[fi] = *(const short8*)(W2T + (size_t)((((kgs + 1) * 64 + rt * 16 + wr * 4 + fi) * 64 + lane) * 8));
    }
    short8 bb = *(const short8*)((const char*)Xl + swz512(bcol, 64 * kgs + rdk));
#pragma unroll
    for (int fi = 0; fi < 4; ++fi)
      acc[fi] = __builtin_amdgcn_mfma_f32_16x16x32_bf16(a_cur[fi], bb, acc[fi], 0, 0, 0);
#pragma unroll
    for (int fi = 0; fi < 4; ++fi) a_cur[fi] = a_nxt[fi];
  }
#pragma unroll
  for (int fi = 0; fi < 4; ++fi) {
#pragma unroll
    for (int r = 0; r < 4; ++r) {
      const int rr = rt * 256 + wr * 64 + fi * 16 + (lane >> 4) * 4 + r;
      qWbuf[(size_t)(b * 1024 + rr) * M_ + m0 + bcol] = f2bf(acc[fi][r] + qb2[rr]);
    }
  }
}

// ---- fused_attn: scores + softmax + psum + PV + merge-GEMM -----------------------------
// grid = B*256 = 512 blocks (XCD-chunked), 1024 threads (16 waves), LDS 72 KB -> 2 bl/CU.
// DENSE wave-loads: wave w, iter i -> channel c = i*16+w read as ONE contiguous 1 KB load
// (lane = m'(4b)|kkq(2b), byte lane*16). Cross-channel score reduction via one LDS round
// (scx[16][64][17] f32, 17-pad = conflict-free), softmax in reducer threads, PV pass same
// dense shape, merge GEMM from swizzled pvt (verbatim R10).
__global__ __launch_bounds__(1024, 8)
void fused_attn(const float* __restrict__ key, const float* __restrict__ value,
                const unsigned short* __restrict__ qW, const unsigned short* __restrict__ Wmv,
                const float* __restrict__ btot, float* __restrict__ out,
                float* __restrict__ psum) {
  __shared__ float ldsA[16 * 64 * 17];   // 68 KB: qsl (score) | scx (reduce) | pvt (merge)
  __shared__ float ldsP[16 * 4 * 16];    // 4 KB prob [m'][h][kk]
  unsigned short* qsl = (unsigned short*)ldsA;
  const int tid = threadIdx.x;
  const int lane = tid & 63;
  const int w = tid >> 6;                                    // wave id 0..15
  const int vb = (blockIdx.x & 7) * 64 + (blockIdx.x >> 3);  // 512 = 8 XCD x 64
  const int b = vb >> 8;
  const int m0 = (vb & 255) * 16;
  // ---- stage qW slab: one (h,c) row per thread; [c][slot=(q+c)&15][h] rotation ----
  {
    const int c = tid & 255, h = tid >> 8;
    const unsigned short* src = qW + ((size_t)(b * 1024 + h * 256 + c)) * M_ + m0;
    uint4 rv[2];
    rv[0] = *(const uint4*)(src);
    rv[1] = *(const uint4*)(src + 8);
    const unsigned short* rs = (const unsigned short*)rv;
#pragma unroll
    for (int q = 0; q < 16; ++q) {
      const int slot = (q + c) & 15;
      qsl[c * 64 + slot * 4 + h] = rs[q];
    }
  }
  __syncthreads();
  const int mp = lane >> 2;              // m-local 0..15
  const int kkq = lane & 3;              // kk quarter
  const size_t cbase = (size_t)(b * 256) * 65536 + (size_t)m0 * 16 + lane * 4;
  // ---- score pass: wave w streams channels {i*16+w} as dense 1 KB loads ----
  f32x4 ps0 = {}, ps1 = {}, ps2 = {}, ps3 = {};
#pragma unroll 4
  for (int i = 0; i < 16; ++i) {
    const int c = i * 16 + w;
    const f32x4 kv = *(const f32x4*)(key + cbase + (size_t)c * 65536);
    const int slot = (mp + c) & 15;
    const uint2 qv = *(const uint2*)&qsl[c * 64 + slot * 4];
    ps0 += kv * u2f(qv.x << 16);
    ps1 += kv * u2f(qv.x & 0xffff0000u);
    ps2 += kv * u2f(qv.y << 16);
    ps3 += kv * u2f(qv.y & 0xffff0000u);
  }
  __syncthreads();                       // qsl dead -> scx takes over ldsA
  {
    float* scx = ldsA + w * 1088 + lane * 17;   // 17-pad: conflict-free b32 stores
#pragma unroll
    for (int j = 0; j < 4; ++j) {
      scx[j]      = ps0[j];
      scx[4 + j]  = ps1[j];
      scx[8 + j]  = ps2[j];
      scx[12 + j] = ps3[j];
    }
  }
  __syncthreads();
  // ---- reduce over 16 waves + softmax; thread t = m'(4b)|h(2b)|kk(4b) ----
  {
    const int mp2 = tid >> 6;
    const int h2 = (lane >> 4) & 3;
    const int kk = lane & 15;
    const int lanep = mp2 * 4 + (kk >> 2);
    const int idx = h2 * 4 + (kk & 3);
    float sc = 0.f;
#pragma unroll
    for (int w2 = 0; w2 < 16; ++w2) sc += ldsA[w2 * 1088 + lanep * 17 + idx];
    sc *= 0.125f;                        // 1/sqrt(64)
    float mx = sc;
    mx = fmaxf(mx, __shfl_xor(mx, 1)); mx = fmaxf(mx, __shfl_xor(mx, 2));
    mx = fmaxf(mx, __shfl_xor(mx, 4)); mx = fmaxf(mx, __shfl_xor(mx, 8));
    const float e = __expf(sc - mx);
    float sm = e;
    sm += __shfl_xor(sm, 1); sm += __shfl_xor(sm, 2);
    sm += __shfl_xor(sm, 4); sm += __shfl_xor(sm, 8);
    const float pb = e / sm;
    ldsP[(mp2 * 4 + h2) * 16 + kk] = pb;
    float tot = pb;
    tot += __shfl_xor(tot, 16); tot += __shfl_xor(tot, 32);
    if (lane < 16)                       // h2==0, lane==kk
      psum[((size_t)b * M_ + m0 + mp2) * KN_ + kk] = tot;
  }
  __syncthreads();                       // prob ready; scx dead -> pvt takes over ldsA
  // ---- PV pass: dense value streaming; pvt[m'][k=c*4+h] XOR-swizzled ----
  {
    const f32x4 pr0 = *(const f32x4*)&ldsP[(mp * 4 + 0) * 16 + kkq * 4];
    const f32x4 pr1 = *(const f32x4*)&ldsP[(mp * 4 + 1) * 16 + kkq * 4];
    const f32x4 pr2 = *(const f32x4*)&ldsP[(mp * 4 + 2) * 16 + kkq * 4];
    const f32x4 pr3 = *(const f32x4*)&ldsP[(mp * 4 + 3) * 16 + kkq * 4];
#pragma unroll 4
    for (int i = 0; i < 16; ++i) {
      const int c = i * 16 + w;
      const f32x4 vv = *(const f32x4*)(value + cbase + (size_t)c * 65536);
      float p0 = pr0[0] * vv[0] + pr0[1] * vv[1] + pr0[2] * vv[2] + pr0[3] * vv[3];
      float p1 = pr1[0] * vv[0] + pr1[1] * vv[1] + pr1[2] * vv[2] + pr1[3] * vv[3];
      float p2 = pr2[0] * vv[0] + pr2[1] * vv[1] + pr2[2] * vv[2] + pr2[3] * vv[3];
      float p3 = pr3[0] * vv[0] + pr3[1] * vv[1] + pr3[2] * vv[2] + pr3[3] * vv[3];
      p0 += __shfl_xor(p0, 1); p0 += __shfl_xor(p0, 2);
      p1 += __shfl_xor(p1, 1); p1 += __shfl_xor(p1, 2);
      p2 += __shfl_xor(p2, 1); p2 += __shfl_xor(p2, 2);
      p3 += __shfl_xor(p3, 1); p3 += __shfl_xor(p3, 2);
      if (kkq == 0) {
        uint2 o;
        o.x = (uint32_t)f2bf(p0) | ((uint32_t)f2bf(p1) << 16);
        o.y = (uint32_t)f2bf(p2) | ((uint32_t)f2bf(p3) << 16);
        *(uint2*)((char*)ldsA + ((mp * 2048 + c * 8) ^ ((mp & 7) << 4))) = o;
      }
    }
  }
  __syncthreads();
  // ---- merge GEMM: out[o][m'] = Wmv(256x1024) x pvt(1024x16) + btot ----
  {
    const int wid = tid >> 6;            // A-row-block (rows wid*16..+15)
    const int bcol = lane & 15;          // m'
    const int kgrp = lane >> 4;          // 0..3
    f32x4 acc = {};
    for (int kgs = 0; kgs < 32; ++kgs) {
      const int byte = (bcol * 2048 + kgs * 64 + kgrp * 16) ^ ((bcol & 7) << 4);
      const short8 bb = *(const short8*)((const char*)ldsA + byte);
      const short8 a0 = *(const short8*)(Wmv + (size_t)(((kgs * 16 + wid) * 64 + lane) * 8));
      acc = __builtin_amdgcn_mfma_f32_16x16x32_bf16(a0, bb, acc, 0, 0, 0);
    }
#pragma unroll
    for (int r = 0; r < 4; ++r) {
      const int o = wid * 16 + kgrp * 4 + r;
      out[((size_t)(b * DM_ + o)) * M_ + m0 + bcol] = acc[r] + btot[o];
    }
  }
}

extern "C" void kernel_launch(void* const* d_in, const int* in_sizes, int n_in,
                              void* d_out, int out_size, void* d_ws, size_t ws_size,
                              hipStream_t stream) {
  const float* query = (const float*)d_in[0];
  const float* key   = (const float*)d_in[1];
  const float* value = (const float*)d_in[2];
  const float* Wq = (const float*)d_in[3];
  const float* bq = (const float*)d_in[4];
  const float* Wk = (const float*)d_in[5];
  const float* bk = (const float*)d_in[6];  (void)bk;  // folded: softmax-invariant
  const float* Wv = (const float*)d_in[7];
  const float* bv = (const float*)d_in[8];
  const float* Wm = (const float*)d_in[9];
  const float* bm = (const float*)d_in[10];
  float* out  = (float*)d_out;
  float* psum = out + (size_t)B_ * DM_ * M_;   // outputs concatenated: out then prob_sum

  // ---- workspace layout (17.8 MB) ----
  const size_t Wmv_off  = 524288;
  const size_t qb2_off  = 1048576;
  const size_t btot_off = 1052672;
  const size_t qW_off   = 1053696;             // qW: 16.78 MB bf16

  unsigned short* W2T   = (unsigned short*)d_ws;
  unsigned short* Wmv   = (unsigned short*)((char*)d_ws + Wmv_off);
  float* qb2            = (float*)((char*)d_ws + qb2_off);
  float* btot           = (float*)((char*)d_ws + btot_off);
  unsigned short* qWbuf = (unsigned short*)((char*)d_ws + qW_off);

  prep2<<<dim3(1027), dim3(512), 0, stream>>>(Wq, bq, Wk, Wv, bv, Wm, bm, W2T, Wmv, qb2, btot);
  qw_gemm<<<dim3(B_ * 4 * 128), dim3(512), 0, stream>>>(query, W2T, qb2, qWbuf);
  fused_attn<<<dim3(512), dim3(1024), 0, stream>>>(key, value, qWbuf, Wmv, btot, out, psum);
}